// Round 3
// baseline (1227.888 us; speedup 1.0000x reference)
//
#include <hip/hip_runtime.h>
#include <math.h>
#include <stdint.h>

#define DDIM 512
#define QN   256
#define MT   256            // rows per chunk = 16 waves x 16 rows
#define WAVES 16
#define NT   1024
#define KNN  5
#define BK   32
#define NSTEP (DDIM / BK)   // 16
#define WROW 80             // padded LDS row stride (bytes) for 32 bf16 cols
#define QTILE_B (QN * WROW) // 20480 bytes per buffer
#define BIGF 3.0e38f

typedef __attribute__((ext_vector_type(8))) short bf16x8;
typedef __attribute__((ext_vector_type(4))) float f32x4;

__device__ __forceinline__ unsigned short f2bf(float x) {
    union { float f; unsigned u; } c; c.f = x;
    unsigned r = c.u + 0x7FFFu + ((c.u >> 16) & 1u);   // RNE
    return (unsigned short)(r >> 16);
}

// Sorted top-5 insert (ascending; s[4] = worst). Static indices only.
__device__ __forceinline__ void t5_insert(float (&s)[KNN], int (&ix)[KNN], float v, int vi) {
    if (v < s[4]) {
        s[4] = v; ix[4] = vi;
        if (s[4] < s[3]) { float t = s[3]; s[3] = s[4]; s[4] = t; int u = ix[3]; ix[3] = ix[4]; ix[4] = u; }
        if (s[3] < s[2]) { float t = s[2]; s[2] = s[3]; s[3] = t; int u = ix[2]; ix[2] = ix[3]; ix[3] = u; }
        if (s[2] < s[1]) { float t = s[1]; s[1] = s[2]; s[2] = t; int u = ix[1]; ix[1] = ix[2]; ix[2] = u; }
        if (s[1] < s[0]) { float t = s[0]; s[0] = s[1]; s[1] = t; int u = ix[0]; ix[0] = ix[1]; ix[1] = u; }
    }
}

// Phase 0: queries f32 -> bf16 (256 KB, L2-resident afterwards)
__global__ void conv_q(const float* __restrict__ emb, unsigned short* __restrict__ qbf) {
    int i = blockIdx.x * 256 + threadIdx.x;      // covers QN*DDIM/4 = 32768
    float4 v = ((const float4*)emb)[i];
    ushort4 o;
    o.x = f2bf(v.x); o.y = f2bf(v.y); o.z = f2bf(v.z); o.w = f2bf(v.w);
    ((ushort4*)qbf)[i] = o;
}

// Phase A: per 256-row chunk, score = ||m||^2 - 2 q.m for all 256 queries via
// bf16 MFMA. 16 waves x 16 rows; q tile double-buffered in LDS (padded rows);
// one barrier per K-step; A rows f32->reg->bf16 exactly once.
__global__ __launch_bounds__(NT, 4) void knn_partial(
        const float* __restrict__ mem, const unsigned short* __restrict__ qbf,
        float2* __restrict__ cand, int N, int NC) {
    __shared__ char   smq[2 * QTILE_B];          // 40 KB
    __shared__ float  smsq[MT];                  // 1 KB
    __shared__ float2 mbuf[WAVES][16][KNN];      // 10 KB

    const int tid  = threadIdx.x;
    const int lane = tid & 63;
    const int w    = tid >> 6;
    const int l15  = lane & 15;
    const int lq   = lane >> 4;
    const int chunk = blockIdx.x;
    const int rbase = chunk * MT + w * 16;

    // A source: global row rbase+l15, k-slice lq*8
    int gr = rbase + l15; if (gr >= N) gr = N - 1;
    const float* pA = mem + (size_t)gr * DDIM + lq * 8;

    // q staging: thread covers (row tid>>2, cols (tid&3)*8 .. +7)
    const unsigned short* qsrc = qbf + (size_t)(tid >> 2) * DDIM + (tid & 3) * 8;
    const int wbyte = (tid >> 2) * WROW + (tid & 3) * 16;
    const int rbyte = l15 * WROW + lq * 16;      // + g*16*WROW + buf

    f32x4 acc[16];
    const f32x4 zero4 = {0.f, 0.f, 0.f, 0.f};
#pragma unroll
    for (int g = 0; g < 16; ++g) acc[g] = zero4;
    float sq = 0.f;

    // prologue: step 0 into buffer 0
    uint4  qv  = *(const uint4*)qsrc;
    float4 av0 = *(const float4*)(pA);
    float4 av1 = *(const float4*)(pA + 4);
    *(uint4*)(smq + wbyte) = qv;
    __syncthreads();

    for (int s = 0; s < NSTEP; ++s) {
        const int cur = (s & 1) ? QTILE_B : 0;
        uint4 qn; float4 an0, an1;
        if (s + 1 < NSTEP) {                         // issue next-step loads early
            qn  = *(const uint4*)(qsrc + (s + 1) * BK);
            an0 = *(const float4*)(pA + (s + 1) * BK);
            an1 = *(const float4*)(pA + (s + 1) * BK + 4);
        }
        // convert current A (loaded last iter; latency long hidden) + ||m||^2
        bf16x8 a;
        a[0] = (short)f2bf(av0.x); a[1] = (short)f2bf(av0.y);
        a[2] = (short)f2bf(av0.z); a[3] = (short)f2bf(av0.w);
        a[4] = (short)f2bf(av1.x); a[5] = (short)f2bf(av1.y);
        a[6] = (short)f2bf(av1.z); a[7] = (short)f2bf(av1.w);
        sq = fmaf(av0.x, av0.x, sq); sq = fmaf(av0.y, av0.y, sq);
        sq = fmaf(av0.z, av0.z, sq); sq = fmaf(av0.w, av0.w, sq);
        sq = fmaf(av1.x, av1.x, sq); sq = fmaf(av1.y, av1.y, sq);
        sq = fmaf(av1.z, av1.z, sq); sq = fmaf(av1.w, av1.w, sq);

        const char* rp = smq + cur + rbyte;
#pragma unroll
        for (int g = 0; g < 16; ++g) {
            bf16x8 b = *(const bf16x8*)(rp + g * (16 * WROW));
            acc[g] = __builtin_amdgcn_mfma_f32_16x16x32_bf16(a, b, acc[g], 0, 0, 0);
        }
        if (s + 1 < NSTEP) {
            *(uint4*)(smq + (cur ^ QTILE_B) + wbyte) = qn;   // waits only on qn (L2)
            av0 = an0; av1 = an1;
        }
        __syncthreads();   // one barrier per step (dbuf makes this sufficient)
    }

    // ||m||^2 per row: reduce k-slices across lq
    sq += __shfl_xor(sq, 16);
    sq += __shfl_xor(sq, 32);
    if (lane < 16) smsq[w * 16 + lane] = sq;
    __syncthreads();
    float4 rsqv = *(const float4*)&smsq[w * 16 + lq * 4];
    float rsqa[4] = {rsqv.x, rsqv.y, rsqv.z, rsqv.w};
    const int rrow = rbase + lq * 4;

    // per q-group: scores -> lane top5 -> shfl merge -> staged cross-wave merge
#pragma unroll
    for (int g = 0; g < 16; ++g) {
        float ts[KNN] = {BIGF, BIGF, BIGF, BIGF, BIGF};
        int   ti[KNN] = {0, 0, 0, 0, 0};
#pragma unroll
        for (int e = 0; e < 4; ++e) {
            int grow = rrow + e;
            if (grow < N) {
                float sc = fmaf(-2.f, acc[g][e], rsqa[e]);
                t5_insert(ts, ti, sc, grow);
            }
        }
#pragma unroll
        for (int x = 16; x <= 32; x <<= 1) {
            float os[KNN]; int oi[KNN];
#pragma unroll
            for (int c = 0; c < KNN; ++c) { os[c] = __shfl_xor(ts[c], x); oi[c] = __shfl_xor(ti[c], x); }
#pragma unroll
            for (int c = 0; c < KNN; ++c) t5_insert(ts, ti, os[c], oi[c]);
        }
        __syncthreads();   // mbuf free (previous slice's merge done)
        if (lane < 16) {
#pragma unroll
            for (int c = 0; c < KNN; ++c)
                mbuf[w][lane][c] = make_float2(ts[c], __int_as_float(ti[c]));
        }
        __syncthreads();   // slice g complete
        if (w == g) {      // wave g merges slice g while others move on
            float fs[KNN] = {BIGF, BIGF, BIGF, BIGF, BIGF};
            int   fi[KNN] = {0, 0, 0, 0, 0};
#pragma unroll
            for (int v = 0; v < 4; ++v) {
#pragma unroll
                for (int c = 0; c < KNN; ++c) {
                    float2 e2 = mbuf[lq * 4 + v][l15][c];
                    t5_insert(fs, fi, e2.x, __float_as_int(e2.y));
                }
            }
#pragma unroll
            for (int x = 16; x <= 32; x <<= 1) {
                float os[KNN]; int oi[KNN];
#pragma unroll
                for (int c = 0; c < KNN; ++c) { os[c] = __shfl_xor(fs[c], x); oi[c] = __shfl_xor(fi[c], x); }
#pragma unroll
                for (int c = 0; c < KNN; ++c) t5_insert(fs, fi, os[c], oi[c]);
            }
            if (lane < 16) {
                float2* dst = cand + ((size_t)(g * 16 + lane) * NC + chunk) * KNN;
#pragma unroll
                for (int c = 0; c < KNN; ++c) dst[c] = make_float2(fs[c], __int_as_float(fi[c]));
            }
        }
    }
}

// Phase B: one wave per query: global top-5 over NC*5 candidates, gather rows,
// exact f32 distances (immune to bf16 ranking jitter), per-query sum.
__global__ void knn_merge_exact(const float* __restrict__ emb, const float* __restrict__ mem,
                                const float2* __restrict__ cand, float* __restrict__ qsum,
                                int Q, int NC) {
    const int q = blockIdx.x;
    const int lane = threadIdx.x;  // 64
    float fs[KNN] = {BIGF, BIGF, BIGF, BIGF, BIGF};
    int   fi[KNN] = {0, 0, 0, 0, 0};
    const float2* qc = cand + (size_t)q * NC * KNN;
    for (int c = lane; c < NC; c += 64) {
        const float2* p = qc + (size_t)c * KNN;
#pragma unroll
        for (int k = 0; k < KNN; ++k) {
            float2 e = p[k];
            t5_insert(fs, fi, e.x, __float_as_int(e.y));
        }
    }
    __shared__ float2 ls[64][KNN];
    __shared__ int sel[KNN];
#pragma unroll
    for (int k = 0; k < KNN; ++k) ls[lane][k] = make_float2(fs[k], __int_as_float(fi[k]));
    __syncthreads();
    if (lane == 0) {
        float gs[KNN] = {BIGF, BIGF, BIGF, BIGF, BIGF};
        int   gi[KNN] = {0, 0, 0, 0, 0};
        for (int l = 0; l < 64; ++l)
#pragma unroll
            for (int k = 0; k < KNN; ++k)
                t5_insert(gs, gi, ls[l][k].x, __float_as_int(ls[l][k].y));
#pragma unroll
        for (int k = 0; k < KNN; ++k) sel[k] = gi[k];
    }
    __syncthreads();
    const float4* qp = (const float4*)(emb + (size_t)q * DDIM);
    float4 q0 = qp[lane * 2], q1 = qp[lane * 2 + 1];
    float ssum = 0.f;
    for (int k = 0; k < KNN; ++k) {
        const float4* mp = (const float4*)(mem + (size_t)sel[k] * DDIM);
        float4 m0 = mp[lane * 2], m1 = mp[lane * 2 + 1];
        float d0 = m0.x - q0.x, d1 = m0.y - q0.y, d2 = m0.z - q0.z, d3 = m0.w - q0.w;
        float d4 = m1.x - q1.x, d5 = m1.y - q1.y, d6 = m1.z - q1.z, d7 = m1.w - q1.w;
        float t = d0 * d0 + d1 * d1 + d2 * d2 + d3 * d3 + d4 * d4 + d5 * d5 + d6 * d6 + d7 * d7;
#pragma unroll
        for (int off = 32; off > 0; off >>= 1) t += __shfl_down(t, off);
        if (lane == 0) ssum += sqrtf(t);
    }
    if (lane == 0) qsum[q] = ssum;
}

__global__ void knn_reduce(const float* __restrict__ qsum, float* __restrict__ out, int Q) {
    const int lane = threadIdx.x;
    float v = 0.f;
    for (int i = lane; i < Q; i += 64) v += qsum[i];
#pragma unroll
    for (int off = 32; off > 0; off >>= 1) v += __shfl_down(v, off);
    if (lane == 0) out[0] = v / (float)(Q * KNN);
}

extern "C" void kernel_launch(void* const* d_in, const int* in_sizes, int n_in,
                              void* d_out, int out_size, void* d_ws, size_t ws_size,
                              hipStream_t stream) {
    (void)n_in; (void)out_size; (void)ws_size;
    const float* emb = (const float*)d_in[0];
    const float* mem = (const float*)d_in[1];
    const int Q  = in_sizes[0] / DDIM;       // 256
    const int N  = in_sizes[1] / DDIM;       // 200000
    const int NC = (N + MT - 1) / MT;        // 782

    float2*         cand = (float2*)d_ws;                                        // Q*NC*5*8B ~ 8 MB
    float*          qsum = (float*)((char*)d_ws + (size_t)Q * NC * KNN * 8);     // 1 KB
    unsigned short* qbf  = (unsigned short*)((char*)d_ws + (size_t)Q * NC * KNN * 8 + 1024);

    conv_q<<<(Q * DDIM / 4 + 255) / 256, 256, 0, stream>>>(emb, qbf);
    knn_partial<<<NC, NT, 0, stream>>>(mem, qbf, cand, N, NC);
    knn_merge_exact<<<Q, 64, 0, stream>>>(emb, mem, cand, qsum, Q, NC);
    knn_reduce<<<1, 64, 0, stream>>>(qsum, (float*)d_out, Q);
}

// Round 4
// 368.557 us; speedup vs baseline: 3.3316x; 3.3316x over previous
//
#include <hip/hip_runtime.h>
#include <math.h>
#include <stdint.h>

#define DDIM 512
#define QN   256
#define MT   256            // rows per chunk (block) = 4 groups x 64
#define GRPS 4
#define GROWS 64            // rows per group = 4 waves x 16
#define WAVES 4
#define NT   256
#define KNN  5
#define BK   32
#define NSTEP (DDIM / BK)   // 16
#define WROW 80             // padded LDS row stride (bytes) for 32 bf16 cols
#define QTILE_B (QN * WROW) // 20480 bytes per buffer
#define BIGF 3.0e38f

typedef __attribute__((ext_vector_type(8))) short bf16x8;
typedef __attribute__((ext_vector_type(4))) float f32x4;

__device__ __forceinline__ unsigned short f2bf(float x) {
    union { float f; unsigned u; } c; c.f = x;
    unsigned r = c.u + 0x7FFFu + ((c.u >> 16) & 1u);   // RNE
    return (unsigned short)(r >> 16);
}

// Sorted top-5 insert (ascending; s[4] = worst). Static indices only.
__device__ __forceinline__ void t5_insert(float (&s)[KNN], int (&ix)[KNN], float v, int vi) {
    if (v < s[4]) {
        s[4] = v; ix[4] = vi;
        if (s[4] < s[3]) { float t = s[3]; s[3] = s[4]; s[4] = t; int u = ix[3]; ix[3] = ix[4]; ix[4] = u; }
        if (s[3] < s[2]) { float t = s[2]; s[2] = s[3]; s[3] = t; int u = ix[2]; ix[2] = ix[3]; ix[3] = u; }
        if (s[2] < s[1]) { float t = s[1]; s[1] = s[2]; s[2] = t; int u = ix[1]; ix[1] = ix[2]; ix[2] = u; }
        if (s[1] < s[0]) { float t = s[0]; s[0] = s[1]; s[1] = t; int u = ix[0]; ix[0] = ix[1]; ix[1] = u; }
    }
}

// Phase 0: queries f32 -> bf16 (256 KB, L2-resident afterwards)
__global__ void conv_q(const float* __restrict__ emb, unsigned short* __restrict__ qbf) {
    int i = blockIdx.x * 256 + threadIdx.x;      // covers QN*DDIM/4 = 32768
    float4 v = ((const float4*)emb)[i];
    ushort4 o;
    o.x = f2bf(v.x); o.y = f2bf(v.y); o.z = f2bf(v.z); o.w = f2bf(v.w);
    ((ushort4*)qbf)[i] = o;
}

// Phase A: per 256-row chunk (4 sequential 64-row groups), score =
// ||m||^2 - 2 q.m for all 256 queries via bf16 MFMA. 4 waves x 16 rows;
// q tile double-buffered in padded LDS; one barrier per K-step; running
// per-query top-5 carried in thread-q registers across groups.
__global__ __launch_bounds__(NT, 3) void knn_partial(
        const float* __restrict__ mem, const unsigned short* __restrict__ qbf,
        float2* __restrict__ cand, int N, int NC) {
    __shared__ union {
        char   q[2 * QTILE_B];                 // 40960 B (K-loop)
        float2 mbuf[WAVES][16][16][KNN];       // 40960 B (merge, after K-loop)
    } sm;
    __shared__ float smsq[GROWS];

    const int tid  = threadIdx.x;
    const int lane = tid & 63;
    const int w    = tid >> 6;                 // 0..3
    const int l15  = lane & 15;
    const int lq   = lane >> 4;                // k-slice 0..3
    const int chunk = blockIdx.x;

    // q staging: piece p covers (row (tid>>2)+p*64, cols (tid&3)*8..+7)
    const unsigned short* qsrc = qbf + (size_t)(tid >> 2) * DDIM + (tid & 3) * 8;
    const int wbyte = (tid >> 2) * WROW + (tid & 3) * 16;   // + p*64*WROW
    const int rbyte = l15 * WROW + lq * 16;                 // + g*16*WROW + buf

    float fs[KNN] = {BIGF, BIGF, BIGF, BIGF, BIGF};
    int   fi[KNN] = {0, 0, 0, 0, 0};

#pragma unroll 1
    for (int grp = 0; grp < GRPS; ++grp) {
        const int rbase = chunk * MT + grp * GROWS;
        int gr = rbase + w * 16 + l15; if (gr >= N) gr = N - 1;
        const float* pA = mem + (size_t)gr * DDIM + lq * 8;

        f32x4 acc[16];
        const f32x4 zero4 = {0.f, 0.f, 0.f, 0.f};
#pragma unroll
        for (int g = 0; g < 16; ++g) acc[g] = zero4;
        float sq = 0.f;

        // prologue: step 0 into buffer 0
        uint4 qv[4];
#pragma unroll
        for (int p = 0; p < 4; ++p)
            qv[p] = *(const uint4*)(qsrc + (size_t)p * 64 * DDIM);
        float4 av0 = *(const float4*)(pA);
        float4 av1 = *(const float4*)(pA + 4);
#pragma unroll
        for (int p = 0; p < 4; ++p)
            *(uint4*)(sm.q + wbyte + p * 64 * WROW) = qv[p];
        __syncthreads();

        for (int s = 0; s < NSTEP; ++s) {
            const int cur = (s & 1) ? QTILE_B : 0;
            uint4 qn[4]; float4 an0, an1;
            if (s + 1 < NSTEP) {
#pragma unroll
                for (int p = 0; p < 4; ++p)
                    qn[p] = *(const uint4*)(qsrc + (size_t)p * 64 * DDIM + (s + 1) * BK);
                an0 = *(const float4*)(pA + (s + 1) * BK);
                an1 = *(const float4*)(pA + (s + 1) * BK + 4);
            }
            // convert current A rows + ||m||^2 partial (each element once)
            bf16x8 a;
            a[0] = (short)f2bf(av0.x); a[1] = (short)f2bf(av0.y);
            a[2] = (short)f2bf(av0.z); a[3] = (short)f2bf(av0.w);
            a[4] = (short)f2bf(av1.x); a[5] = (short)f2bf(av1.y);
            a[6] = (short)f2bf(av1.z); a[7] = (short)f2bf(av1.w);
            sq = fmaf(av0.x, av0.x, sq); sq = fmaf(av0.y, av0.y, sq);
            sq = fmaf(av0.z, av0.z, sq); sq = fmaf(av0.w, av0.w, sq);
            sq = fmaf(av1.x, av1.x, sq); sq = fmaf(av1.y, av1.y, sq);
            sq = fmaf(av1.z, av1.z, sq); sq = fmaf(av1.w, av1.w, sq);

            const char* rp = sm.q + cur + rbyte;
#pragma unroll
            for (int g = 0; g < 16; ++g) {
                bf16x8 b = *(const bf16x8*)(rp + g * (16 * WROW));
                acc[g] = __builtin_amdgcn_mfma_f32_16x16x32_bf16(a, b, acc[g], 0, 0, 0);
            }
            if (s + 1 < NSTEP) {
#pragma unroll
                for (int p = 0; p < 4; ++p)
                    *(uint4*)(sm.q + (cur ^ QTILE_B) + wbyte + p * 64 * WROW) = qn[p];
                av0 = an0; av1 = an1;
            }
            __syncthreads();
        }

        // ||m||^2 per row (reduce k-slices across lq)
        sq += __shfl_xor(sq, 16);
        sq += __shfl_xor(sq, 32);
        if (lane < 16) smsq[w * 16 + lane] = sq;
        __syncthreads();
        float rsqa[4];
#pragma unroll
        for (int e = 0; e < 4; ++e) rsqa[e] = smsq[w * 16 + lq * 4 + e];
        const int rrow = rbase + w * 16 + lq * 4;

        // per q-group: scores -> lane top5 -> shfl merge -> mbuf (aliases smq)
#pragma unroll
        for (int g = 0; g < 16; ++g) {
            float ts[KNN] = {BIGF, BIGF, BIGF, BIGF, BIGF};
            int   ti[KNN] = {0, 0, 0, 0, 0};
#pragma unroll
            for (int e = 0; e < 4; ++e) {
                int grow = rrow + e;
                if (grow < N) {
                    float sc = fmaf(-2.f, acc[g][e], rsqa[e]);
                    t5_insert(ts, ti, sc, grow);
                }
            }
#pragma unroll
            for (int x = 16; x <= 32; x <<= 1) {
                float os[KNN]; int oi[KNN];
#pragma unroll
                for (int c = 0; c < KNN; ++c) { os[c] = __shfl_xor(ts[c], x); oi[c] = __shfl_xor(ti[c], x); }
#pragma unroll
                for (int c = 0; c < KNN; ++c) t5_insert(ts, ti, os[c], oi[c]);
            }
            if (lane < 16) {
#pragma unroll
                for (int c = 0; c < KNN; ++c)
                    sm.mbuf[w][g][lane][c] = make_float2(ts[c], __int_as_float(ti[c]));
            }
        }
        __syncthreads();
        // thread q = tid merges the 4 waves' top5 into its running top5
#pragma unroll
        for (int ww = 0; ww < WAVES; ++ww)
#pragma unroll
            for (int c = 0; c < KNN; ++c) {
                float2 e2 = sm.mbuf[ww][tid >> 4][tid & 15][c];
                t5_insert(fs, fi, e2.x, __float_as_int(e2.y));
            }
        __syncthreads();   // protect sm reuse by next group
    }

    float2* dst = cand + ((size_t)tid * NC + chunk) * KNN;
#pragma unroll
    for (int c = 0; c < KNN; ++c) dst[c] = make_float2(fs[c], __int_as_float(fi[c]));
}

// Phase B: one wave per query: global top-5 over NC*5 candidates, gather rows,
// exact f32 distances (immune to bf16 ranking jitter), per-query sum.
__global__ void knn_merge_exact(const float* __restrict__ emb, const float* __restrict__ mem,
                                const float2* __restrict__ cand, float* __restrict__ qsum,
                                int Q, int NC) {
    const int q = blockIdx.x;
    const int lane = threadIdx.x;  // 64
    float fs[KNN] = {BIGF, BIGF, BIGF, BIGF, BIGF};
    int   fi[KNN] = {0, 0, 0, 0, 0};
    const float2* qc = cand + (size_t)q * NC * KNN;
    for (int c = lane; c < NC; c += 64) {
        const float2* p = qc + (size_t)c * KNN;
#pragma unroll
        for (int k = 0; k < KNN; ++k) {
            float2 e = p[k];
            t5_insert(fs, fi, e.x, __float_as_int(e.y));
        }
    }
    __shared__ float2 ls[64][KNN];
    __shared__ int sel[KNN];
#pragma unroll
    for (int k = 0; k < KNN; ++k) ls[lane][k] = make_float2(fs[k], __int_as_float(fi[k]));
    __syncthreads();
    if (lane == 0) {
        float gs[KNN] = {BIGF, BIGF, BIGF, BIGF, BIGF};
        int   gi[KNN] = {0, 0, 0, 0, 0};
        for (int l = 0; l < 64; ++l)
#pragma unroll
            for (int k = 0; k < KNN; ++k)
                t5_insert(gs, gi, ls[l][k].x, __float_as_int(ls[l][k].y));
#pragma unroll
        for (int k = 0; k < KNN; ++k) sel[k] = gi[k];
    }
    __syncthreads();
    const float4* qp = (const float4*)(emb + (size_t)q * DDIM);
    float4 q0 = qp[lane * 2], q1 = qp[lane * 2 + 1];
    float ssum = 0.f;
    for (int k = 0; k < KNN; ++k) {
        const float4* mp = (const float4*)(mem + (size_t)sel[k] * DDIM);
        float4 m0 = mp[lane * 2], m1 = mp[lane * 2 + 1];
        float d0 = m0.x - q0.x, d1 = m0.y - q0.y, d2 = m0.z - q0.z, d3 = m0.w - q0.w;
        float d4 = m1.x - q1.x, d5 = m1.y - q1.y, d6 = m1.z - q1.z, d7 = m1.w - q1.w;
        float t = d0 * d0 + d1 * d1 + d2 * d2 + d3 * d3 + d4 * d4 + d5 * d5 + d6 * d6 + d7 * d7;
#pragma unroll
        for (int off = 32; off > 0; off >>= 1) t += __shfl_down(t, off);
        if (lane == 0) ssum += sqrtf(t);
    }
    if (lane == 0) qsum[q] = ssum;
}

__global__ void knn_reduce(const float* __restrict__ qsum, float* __restrict__ out, int Q) {
    const int lane = threadIdx.x;
    float v = 0.f;
    for (int i = lane; i < Q; i += 64) v += qsum[i];
#pragma unroll
    for (int off = 32; off > 0; off >>= 1) v += __shfl_down(v, off);
    if (lane == 0) out[0] = v / (float)(Q * KNN);
}

extern "C" void kernel_launch(void* const* d_in, const int* in_sizes, int n_in,
                              void* d_out, int out_size, void* d_ws, size_t ws_size,
                              hipStream_t stream) {
    (void)n_in; (void)out_size; (void)ws_size;
    const float* emb = (const float*)d_in[0];
    const float* mem = (const float*)d_in[1];
    const int Q  = in_sizes[0] / DDIM;       // 256
    const int N  = in_sizes[1] / DDIM;       // 200000
    const int NC = (N + MT - 1) / MT;        // 782

    float2*         cand = (float2*)d_ws;                                        // Q*NC*5*8B ~ 8 MB
    float*          qsum = (float*)((char*)d_ws + (size_t)Q * NC * KNN * 8);     // 1 KB
    unsigned short* qbf  = (unsigned short*)((char*)d_ws + (size_t)Q * NC * KNN * 8 + 1024);

    conv_q<<<(Q * DDIM / 4 + 255) / 256, 256, 0, stream>>>(emb, qbf);
    knn_partial<<<NC, NT, 0, stream>>>(mem, qbf, cand, N, NC);
    knn_merge_exact<<<Q, 64, 0, stream>>>(emb, mem, cand, qsum, Q, NC);
    knn_reduce<<<1, 64, 0, stream>>>(qsum, (float*)d_out, Q);
}

// Round 5
// 275.473 us; speedup vs baseline: 4.4574x; 1.3379x over previous
//
#include <hip/hip_runtime.h>
#include <hip/hip_bf16.h>
#include <math.h>
#include <stdint.h>

#define DDIM 512
#define QN   256
#define MT   64             // rows per block = 4 waves x 16
#define WAVES 4
#define NT   256
#define KNN  5
#define BK   32
#define NSTEP (DDIM / BK)   // 16
#define WROW 80             // padded LDS row stride (bytes) for 32 bf16 cols
#define QTILE_B (QN * WROW) // 20480 bytes
#define BIGF 3.0e38f

typedef __attribute__((ext_vector_type(8))) short bf16x8;
typedef __attribute__((ext_vector_type(4))) float f32x4;

// Packed top-5 insert (score with idx in low 6 mantissa bits). Static idx only.
__device__ __forceinline__ void t5p_insert(float (&s)[KNN], float v) {
    if (v < s[4]) {
        s[4] = v;
        if (s[4] < s[3]) { float t = s[3]; s[3] = s[4]; s[4] = t; }
        if (s[3] < s[2]) { float t = s[2]; s[2] = s[3]; s[3] = t; }
        if (s[2] < s[1]) { float t = s[1]; s[1] = s[2]; s[2] = t; }
        if (s[1] < s[0]) { float t = s[0]; s[0] = s[1]; s[1] = t; }
    }
}

// Sorted top-5 insert with explicit index (phase B).
__device__ __forceinline__ void t5_insert(float (&s)[KNN], int (&ix)[KNN], float v, int vi) {
    if (v < s[4]) {
        s[4] = v; ix[4] = vi;
        if (s[4] < s[3]) { float t = s[3]; s[3] = s[4]; s[4] = t; int u = ix[3]; ix[3] = ix[4]; ix[4] = u; }
        if (s[3] < s[2]) { float t = s[2]; s[2] = s[3]; s[3] = t; int u = ix[2]; ix[2] = ix[3]; ix[3] = u; }
        if (s[2] < s[1]) { float t = s[1]; s[1] = s[2]; s[2] = t; int u = ix[1]; ix[1] = ix[2]; ix[2] = u; }
        if (s[1] < s[0]) { float t = s[0]; s[0] = s[1]; s[1] = t; int u = ix[0]; ix[0] = ix[1]; ix[1] = u; }
    }
}

// Phase 0: queries f32 -> bf16 (256 KB, L2-resident afterwards)
__global__ void conv_q(const float* __restrict__ emb, unsigned short* __restrict__ qbf) {
    int i = blockIdx.x * 256 + threadIdx.x;      // covers QN*DDIM/4 = 32768
    float4 v = ((const float4*)emb)[i];
    union { ushort4 u; __hip_bfloat162 h[2]; } o;
    o.h[0] = __float22bfloat162_rn(make_float2(v.x, v.y));
    o.h[1] = __float22bfloat162_rn(make_float2(v.z, v.w));
    ((ushort4*)qbf)[i] = o.u;
}

// Phase A: per 64-row chunk, score = ||m||^2 - 2 q.m for all 256 queries via
// bf16 MFMA. 4 waves x 16 rows; single-buffered padded q tile; 2 barriers per
// K-step; row idx packed into score's low 6 mantissa bits.
__global__ __launch_bounds__(NT, 4) void knn_partial(
        const float* __restrict__ mem, const unsigned short* __restrict__ qbf,
        float* __restrict__ cand, int N) {
    __shared__ union {
        char  q[QTILE_B];                      // 20480 B (K-loop)
        float mbuf[WAVES][16][16][KNN];        // 20480 B (merge, after K-loop)
    } sm;
    __shared__ float smsq[MT];

    const int tid  = threadIdx.x;
    const int lane = tid & 63;
    const int w    = tid >> 6;                 // 0..3
    const int l15  = lane & 15;
    const int lq   = lane >> 4;                // k-slice 0..3
    const int chunk = blockIdx.x;
    const int rbase = chunk * MT;

    int gr = rbase + w * 16 + l15; if (gr >= N) gr = N - 1;
    const float* pA = mem + (size_t)gr * DDIM + lq * 8;
    const unsigned short* qsrc = qbf + (size_t)(tid >> 2) * DDIM + (tid & 3) * 8;
    const int wbyte = (tid >> 2) * WROW + (tid & 3) * 16;   // + p*64*WROW
    const int rbyte = l15 * WROW + lq * 16;                 // + g*16*WROW

    f32x4 acc[16];
    const f32x4 z4 = {0.f, 0.f, 0.f, 0.f};
#pragma unroll
    for (int g = 0; g < 16; ++g) acc[g] = z4;
    float sq = 0.f;

    // prologue loads for step 0
    uint4 qv0 = *(const uint4*)(qsrc);
    uint4 qv1 = *(const uint4*)(qsrc + (size_t)64  * DDIM);
    uint4 qv2 = *(const uint4*)(qsrc + (size_t)128 * DDIM);
    uint4 qv3 = *(const uint4*)(qsrc + (size_t)192 * DDIM);
    float4 av0 = *(const float4*)(pA);
    float4 av1 = *(const float4*)(pA + 4);

    for (int s = 0; s < NSTEP; ++s) {
        __syncthreads();                       // buffer readers of step s-1 done
        *(uint4*)(sm.q + wbyte)             = qv0;
        *(uint4*)(sm.q + wbyte + 64*WROW)   = qv1;
        *(uint4*)(sm.q + wbyte + 128*WROW)  = qv2;
        *(uint4*)(sm.q + wbyte + 192*WROW)  = qv3;
        if (s + 1 < NSTEP) {                   // prefetch next q slab (L2)
            const int o = (s + 1) * BK;
            qv0 = *(const uint4*)(qsrc + o);
            qv1 = *(const uint4*)(qsrc + (size_t)64  * DDIM + o);
            qv2 = *(const uint4*)(qsrc + (size_t)128 * DDIM + o);
            qv3 = *(const uint4*)(qsrc + (size_t)192 * DDIM + o);
        }
        // convert current A slab (loaded a step ago) + ||m||^2 partials
        union { bf16x8 v; __hip_bfloat162 h[4]; } au;
        au.h[0] = __float22bfloat162_rn(make_float2(av0.x, av0.y));
        au.h[1] = __float22bfloat162_rn(make_float2(av0.z, av0.w));
        au.h[2] = __float22bfloat162_rn(make_float2(av1.x, av1.y));
        au.h[3] = __float22bfloat162_rn(make_float2(av1.z, av1.w));
        bf16x8 a = au.v;
        sq = fmaf(av0.x, av0.x, sq); sq = fmaf(av0.y, av0.y, sq);
        sq = fmaf(av0.z, av0.z, sq); sq = fmaf(av0.w, av0.w, sq);
        sq = fmaf(av1.x, av1.x, sq); sq = fmaf(av1.y, av1.y, sq);
        sq = fmaf(av1.z, av1.z, sq); sq = fmaf(av1.w, av1.w, sq);
        if (s + 1 < NSTEP) {                   // prefetch next A slab (HBM)
            av0 = *(const float4*)(pA + (s + 1) * BK);
            av1 = *(const float4*)(pA + (s + 1) * BK + 4);
        }
        __syncthreads();                       // staging visible
        const char* rp = sm.q + rbyte;
#pragma unroll
        for (int g = 0; g < 16; ++g) {
            bf16x8 b = *(const bf16x8*)(rp + g * (16 * WROW));
            acc[g] = __builtin_amdgcn_mfma_f32_16x16x32_bf16(a, b, acc[g], 0, 0, 0);
        }
    }

    // ||m||^2 per row (reduce k-slices across lq)
    sq += __shfl_xor(sq, 16);
    sq += __shfl_xor(sq, 32);
    if (lane < 16) smsq[w * 16 + lane] = sq;
    __syncthreads();                           // also fences last q-buffer reads
    float rsqa[4];
#pragma unroll
    for (int e = 0; e < 4; ++e) rsqa[e] = smsq[w * 16 + lq * 4 + e];

    // per q-group: packed scores -> lane top5 -> shfl merge -> own mbuf slice
#pragma unroll
    for (int g = 0; g < 16; ++g) {
        float ts[KNN] = {BIGF, BIGF, BIGF, BIGF, BIGF};
#pragma unroll
        for (int e = 0; e < 4; ++e) {
            int rl = w * 16 + lq * 4 + e;      // chunk-local row, 0..63
            if (rbase + rl < N) {
                float sc = fmaf(-2.f, acc[g][e], rsqa[e]);
                float pk = __int_as_float((__float_as_int(sc) & ~63) | rl);
                t5p_insert(ts, pk);
            }
        }
#pragma unroll
        for (int x = 16; x <= 32; x <<= 1) {
            float os[KNN];
#pragma unroll
            for (int c = 0; c < KNN; ++c) os[c] = __shfl_xor(ts[c], x);
#pragma unroll
            for (int c = 0; c < KNN; ++c) t5p_insert(ts, os[c]);
        }
        if (lane < 16) {
#pragma unroll
            for (int c = 0; c < KNN; ++c) sm.mbuf[w][g][lane][c] = ts[c];
        }
    }
    __syncthreads();
    {   // thread tid = query tid: merge 4 waves' top5, coalesced cand write
        float fsv[KNN] = {BIGF, BIGF, BIGF, BIGF, BIGF};
#pragma unroll
        for (int ww = 0; ww < WAVES; ++ww)
#pragma unroll
            for (int c = 0; c < KNN; ++c)
                t5p_insert(fsv, sm.mbuf[ww][tid >> 4][tid & 15][c]);
        float* dst = cand + ((size_t)chunk * QN + tid) * KNN;
#pragma unroll
        for (int c = 0; c < KNN; ++c) dst[c] = fsv[c];
    }
}

// Phase B: one wave per query: global top-5 over NC*5 packed candidates,
// gather rows, exact f32 distances (immune to bf16/packing jitter), sum.
__global__ void knn_merge_exact(const float* __restrict__ emb, const float* __restrict__ mem,
                                const float* __restrict__ cand, float* __restrict__ qsum,
                                int Q, int NC) {
    const int q = blockIdx.x;
    const int lane = threadIdx.x;  // 64
    float fs[KNN] = {BIGF, BIGF, BIGF, BIGF, BIGF};
    int   fi[KNN] = {0, 0, 0, 0, 0};
    for (int c = lane; c < NC; c += 64) {
        const float* p = cand + ((size_t)c * Q + q) * KNN;
#pragma unroll
        for (int k = 0; k < KNN; ++k) {
            float pk = p[k];
            int idx = c * MT + (__float_as_int(pk) & 63);
            t5_insert(fs, fi, pk, idx);
        }
    }
    __shared__ float2 ls[64][KNN];
    __shared__ int sel[KNN];
#pragma unroll
    for (int k = 0; k < KNN; ++k) ls[lane][k] = make_float2(fs[k], __int_as_float(fi[k]));
    __syncthreads();
    if (lane == 0) {
        float gs[KNN] = {BIGF, BIGF, BIGF, BIGF, BIGF};
        int   gi[KNN] = {0, 0, 0, 0, 0};
        for (int l = 0; l < 64; ++l)
#pragma unroll
            for (int k = 0; k < KNN; ++k)
                t5_insert(gs, gi, ls[l][k].x, __float_as_int(ls[l][k].y));
#pragma unroll
        for (int k = 0; k < KNN; ++k) sel[k] = gi[k];
    }
    __syncthreads();
    const float4* qp = (const float4*)(emb + (size_t)q * DDIM);
    float4 q0 = qp[lane * 2], q1 = qp[lane * 2 + 1];
    float ssum = 0.f;
    for (int k = 0; k < KNN; ++k) {
        const float4* mp = (const float4*)(mem + (size_t)sel[k] * DDIM);
        float4 m0 = mp[lane * 2], m1 = mp[lane * 2 + 1];
        float d0 = m0.x - q0.x, d1 = m0.y - q0.y, d2 = m0.z - q0.z, d3 = m0.w - q0.w;
        float d4 = m1.x - q1.x, d5 = m1.y - q1.y, d6 = m1.z - q1.z, d7 = m1.w - q1.w;
        float t = d0 * d0 + d1 * d1 + d2 * d2 + d3 * d3 + d4 * d4 + d5 * d5 + d6 * d6 + d7 * d7;
#pragma unroll
        for (int off = 32; off > 0; off >>= 1) t += __shfl_down(t, off);
        if (lane == 0) ssum += sqrtf(t);
    }
    if (lane == 0) qsum[q] = ssum;
}

__global__ void knn_reduce(const float* __restrict__ qsum, float* __restrict__ out, int Q) {
    const int lane = threadIdx.x;
    float v = 0.f;
    for (int i = lane; i < Q; i += 64) v += qsum[i];
#pragma unroll
    for (int off = 32; off > 0; off >>= 1) v += __shfl_down(v, off);
    if (lane == 0) out[0] = v / (float)(Q * KNN);
}

extern "C" void kernel_launch(void* const* d_in, const int* in_sizes, int n_in,
                              void* d_out, int out_size, void* d_ws, size_t ws_size,
                              hipStream_t stream) {
    (void)n_in; (void)out_size; (void)ws_size;
    const float* emb = (const float*)d_in[0];
    const float* mem = (const float*)d_in[1];
    const int Q  = in_sizes[0] / DDIM;       // 256
    const int N  = in_sizes[1] / DDIM;       // 200000
    const int NC = (N + MT - 1) / MT;        // 3125

    float*          cand = (float*)d_ws;                                         // NC*Q*5*4B = 16 MB
    float*          qsum = (float*)((char*)d_ws + (size_t)NC * Q * KNN * 4);     // 1 KB
    unsigned short* qbf  = (unsigned short*)((char*)d_ws + (size_t)NC * Q * KNN * 4 + 1024);

    conv_q<<<(Q * DDIM / 4 + 255) / 256, 256, 0, stream>>>(emb, qbf);
    knn_partial<<<NC, NT, 0, stream>>>(mem, qbf, cand, N);
    knn_merge_exact<<<Q, 64, 0, stream>>>(emb, mem, cand, qsum, Q, NC);
    knn_reduce<<<1, 64, 0, stream>>>(qsum, (float*)d_out, Q);
}

// Round 6
// 255.437 us; speedup vs baseline: 4.8070x; 1.0784x over previous
//
#include <hip/hip_runtime.h>
#include <hip/hip_bf16.h>
#include <math.h>
#include <stdint.h>

#define DDIM 512
#define QN   256
#define MT   128            // rows per block = 8 waves x 16
#define WAVES 8
#define NT   512
#define KNN  5
#define BK   32
#define NSTEP (DDIM / BK)   // 16
#define WROW 80             // padded LDS row stride (bytes) for 32 bf16 cols
#define QTILE_B (QN * WROW) // 20480 bytes
#define BIGF 3.0e38f

typedef __attribute__((ext_vector_type(8))) short bf16x8;
typedef __attribute__((ext_vector_type(4))) float f32x4;

// K-loop barrier: drain LDS ops only; global prefetches stay in flight
// across the barrier (avoids the vmcnt(0) drain __syncthreads would emit).
#define BAR_LGKM() do { \
    asm volatile("s_waitcnt lgkmcnt(0)" ::: "memory"); \
    __builtin_amdgcn_s_barrier(); \
} while (0)

// Packed top-5 insert (score with idx in low 7 mantissa bits). Static idx only.
__device__ __forceinline__ void t5p_insert(float (&s)[KNN], float v) {
    if (v < s[4]) {
        s[4] = v;
        if (s[4] < s[3]) { float t = s[3]; s[3] = s[4]; s[4] = t; }
        if (s[3] < s[2]) { float t = s[2]; s[2] = s[3]; s[3] = t; }
        if (s[2] < s[1]) { float t = s[1]; s[1] = s[2]; s[2] = t; }
        if (s[1] < s[0]) { float t = s[0]; s[0] = s[1]; s[1] = t; }
    }
}

// Sorted top-5 insert with explicit index (phase B).
__device__ __forceinline__ void t5_insert(float (&s)[KNN], int (&ix)[KNN], float v, int vi) {
    if (v < s[4]) {
        s[4] = v; ix[4] = vi;
        if (s[4] < s[3]) { float t = s[3]; s[3] = s[4]; s[4] = t; int u = ix[3]; ix[3] = ix[4]; ix[4] = u; }
        if (s[3] < s[2]) { float t = s[2]; s[2] = s[3]; s[3] = t; int u = ix[2]; ix[2] = ix[3]; ix[3] = u; }
        if (s[2] < s[1]) { float t = s[1]; s[1] = s[2]; s[2] = t; int u = ix[1]; ix[1] = ix[2]; ix[2] = u; }
        if (s[1] < s[0]) { float t = s[0]; s[0] = s[1]; s[1] = t; int u = ix[0]; ix[0] = ix[1]; ix[1] = u; }
    }
}

// Phase 0: queries f32 -> bf16 (256 KB, L2-resident afterwards)
__global__ void conv_q(const float* __restrict__ emb, unsigned short* __restrict__ qbf) {
    int i = blockIdx.x * 256 + threadIdx.x;      // covers QN*DDIM/4 = 32768
    float4 v = ((const float4*)emb)[i];
    union { ushort4 u; __hip_bfloat162 h[2]; } o;
    o.h[0] = __float22bfloat162_rn(make_float2(v.x, v.y));
    o.h[1] = __float22bfloat162_rn(make_float2(v.z, v.w));
    ((ushort4*)qbf)[i] = o.u;
}

// Phase A: per 128-row chunk, score = ||m||^2 - 2 q.m for all 256 queries via
// bf16 MFMA. 8 waves x 16 rows; single-buffered padded q tile; lgkm-only
// barriers keep global prefetches in flight; idx packed in low 7 mantissa bits.
__global__ __launch_bounds__(NT, 4) void knn_partial(
        const float* __restrict__ mem, const unsigned short* __restrict__ qbf,
        float* __restrict__ cand, int N) {
    __shared__ union {
        char  q[QTILE_B];                      // 20480 B (K-loop)
        float mbuf[WAVES][16][16][KNN];        // 40960 B (merge, after K-loop)
    } sm;
    __shared__ float smsq[MT];

    const int tid  = threadIdx.x;
    const int lane = tid & 63;
    const int w    = tid >> 6;                 // 0..7
    const int l15  = lane & 15;
    const int lq   = lane >> 4;                // k-slice 0..3
    const int chunk = blockIdx.x;
    const int rbase = chunk * MT;

    int gr = rbase + w * 16 + l15; if (gr >= N) gr = N - 1;
    const float* pA = mem + (size_t)gr * DDIM + lq * 8;

    // q staging: piece i = p*512 + tid -> row i>>2, 16B col (i&3); 2 pieces/thread
    const int qrow0 = tid >> 2, qc0 = tid & 3;           // p=0: rows 0..127
    const int qrow1 = 128 + qrow0;                       // p=1: rows 128..255
    const unsigned short* qs0 = qbf + (size_t)qrow0 * DDIM + qc0 * 8;
    const unsigned short* qs1 = qbf + (size_t)qrow1 * DDIM + qc0 * 8;
    const int wb0 = qrow0 * WROW + qc0 * 16;
    const int wb1 = qrow1 * WROW + qc0 * 16;
    const int rbyte = l15 * WROW + lq * 16;              // + g*16*WROW

    f32x4 acc[16];
    const f32x4 z4 = {0.f, 0.f, 0.f, 0.f};
#pragma unroll
    for (int g = 0; g < 16; ++g) acc[g] = z4;
    float sq = 0.f;

    // prologue loads for step 0
    uint4 qv0 = *(const uint4*)(qs0);
    uint4 qv1 = *(const uint4*)(qs1);
    float4 av0 = *(const float4*)(pA);
    float4 av1 = *(const float4*)(pA + 4);

    for (int s = 0; s < NSTEP; ++s) {
        BAR_LGKM();                            // readers of step s-1 done
        *(uint4*)(sm.q + wb0) = qv0;           // waits vmcnt on qv only
        *(uint4*)(sm.q + wb1) = qv1;
        if (s + 1 < NSTEP) {                   // prefetch next q slab (L2)
            const int o = (s + 1) * BK;
            qv0 = *(const uint4*)(qs0 + o);
            qv1 = *(const uint4*)(qs1 + o);
        }
        // convert current A slab (loaded a step ago) + ||m||^2 partials
        union { bf16x8 v; __hip_bfloat162 h[4]; } au;
        au.h[0] = __float22bfloat162_rn(make_float2(av0.x, av0.y));
        au.h[1] = __float22bfloat162_rn(make_float2(av0.z, av0.w));
        au.h[2] = __float22bfloat162_rn(make_float2(av1.x, av1.y));
        au.h[3] = __float22bfloat162_rn(make_float2(av1.z, av1.w));
        bf16x8 a = au.v;
        sq = fmaf(av0.x, av0.x, sq); sq = fmaf(av0.y, av0.y, sq);
        sq = fmaf(av0.z, av0.z, sq); sq = fmaf(av0.w, av0.w, sq);
        sq = fmaf(av1.x, av1.x, sq); sq = fmaf(av1.y, av1.y, sq);
        sq = fmaf(av1.z, av1.z, sq); sq = fmaf(av1.w, av1.w, sq);
        if (s + 1 < NSTEP) {                   // prefetch next A slab (HBM)
            av0 = *(const float4*)(pA + (s + 1) * BK);
            av1 = *(const float4*)(pA + (s + 1) * BK + 4);
        }
        BAR_LGKM();                            // staging visible; vmcnt NOT drained
        const char* rp = sm.q + rbyte;
#pragma unroll
        for (int g = 0; g < 16; ++g) {
            bf16x8 b = *(const bf16x8*)(rp + g * (16 * WROW));
            acc[g] = __builtin_amdgcn_mfma_f32_16x16x32_bf16(a, b, acc[g], 0, 0, 0);
        }
    }

    // ||m||^2 per row (reduce k-slices across lq)
    sq += __shfl_xor(sq, 16);
    sq += __shfl_xor(sq, 32);
    if (lane < 16) smsq[w * 16 + lane] = sq;
    __syncthreads();
    float rsqa[4];
#pragma unroll
    for (int e = 0; e < 4; ++e) rsqa[e] = smsq[w * 16 + lq * 4 + e];

    // per q-group: packed scores -> lane top5 -> shfl merge -> own mbuf slice
#pragma unroll
    for (int g = 0; g < 16; ++g) {
        float ts[KNN] = {BIGF, BIGF, BIGF, BIGF, BIGF};
#pragma unroll
        for (int e = 0; e < 4; ++e) {
            int rl = w * 16 + lq * 4 + e;      // chunk-local row, 0..127
            if (rbase + rl < N) {
                float sc = fmaf(-2.f, acc[g][e], rsqa[e]);
                float pk = __int_as_float((__float_as_int(sc) & ~127) | rl);
                t5p_insert(ts, pk);
            }
        }
#pragma unroll
        for (int x = 16; x <= 32; x <<= 1) {
            float os[KNN];
#pragma unroll
            for (int c = 0; c < KNN; ++c) os[c] = __shfl_xor(ts[c], x);
#pragma unroll
            for (int c = 0; c < KNN; ++c) t5p_insert(ts, os[c]);
        }
        if (lane < 16) {
#pragma unroll
            for (int c = 0; c < KNN; ++c) sm.mbuf[w][g][lane][c] = ts[c];
        }
    }
    __syncthreads();
    if (tid < QN) {   // thread tid = query tid: merge 8 waves' top5, coalesced write
        float fsv[KNN] = {BIGF, BIGF, BIGF, BIGF, BIGF};
#pragma unroll
        for (int ww = 0; ww < WAVES; ++ww)
#pragma unroll
            for (int c = 0; c < KNN; ++c)
                t5p_insert(fsv, sm.mbuf[ww][tid >> 4][tid & 15][c]);
        float* dst = cand + ((size_t)chunk * QN + tid) * KNN;
#pragma unroll
        for (int c = 0; c < KNN; ++c) dst[c] = fsv[c];
    }
}

// Phase B: one wave per query: global top-5 over NC*5 packed candidates,
// gather rows, exact f32 distances (immune to bf16/packing jitter), sum.
__global__ void knn_merge_exact(const float* __restrict__ emb, const float* __restrict__ mem,
                                const float* __restrict__ cand, float* __restrict__ qsum,
                                int Q, int NC) {
    const int q = blockIdx.x;
    const int lane = threadIdx.x;  // 64
    float fs[KNN] = {BIGF, BIGF, BIGF, BIGF, BIGF};
    int   fi[KNN] = {0, 0, 0, 0, 0};
    for (int c = lane; c < NC; c += 64) {
        const float* p = cand + ((size_t)c * Q + q) * KNN;
#pragma unroll
        for (int k = 0; k < KNN; ++k) {
            float pk = p[k];
            int idx = c * MT + (__float_as_int(pk) & 127);
            t5_insert(fs, fi, pk, idx);
        }
    }
    __shared__ float2 ls[64][KNN];
    __shared__ int sel[KNN];
#pragma unroll
    for (int k = 0; k < KNN; ++k) ls[lane][k] = make_float2(fs[k], __int_as_float(fi[k]));
    __syncthreads();
    if (lane == 0) {
        float gs[KNN] = {BIGF, BIGF, BIGF, BIGF, BIGF};
        int   gi[KNN] = {0, 0, 0, 0, 0};
        for (int l = 0; l < 64; ++l)
#pragma unroll
            for (int k = 0; k < KNN; ++k)
                t5_insert(gs, gi, ls[l][k].x, __float_as_int(ls[l][k].y));
#pragma unroll
        for (int k = 0; k < KNN; ++k) sel[k] = gi[k];
    }
    __syncthreads();
    const float4* qp = (const float4*)(emb + (size_t)q * DDIM);
    float4 q0 = qp[lane * 2], q1 = qp[lane * 2 + 1];
    float ssum = 0.f;
    for (int k = 0; k < KNN; ++k) {
        const float4* mp = (const float4*)(mem + (size_t)sel[k] * DDIM);
        float4 m0 = mp[lane * 2], m1 = mp[lane * 2 + 1];
        float d0 = m0.x - q0.x, d1 = m0.y - q0.y, d2 = m0.z - q0.z, d3 = m0.w - q0.w;
        float d4 = m1.x - q1.x, d5 = m1.y - q1.y, d6 = m1.z - q1.z, d7 = m1.w - q1.w;
        float t = d0 * d0 + d1 * d1 + d2 * d2 + d3 * d3 + d4 * d4 + d5 * d5 + d6 * d6 + d7 * d7;
#pragma unroll
        for (int off = 32; off > 0; off >>= 1) t += __shfl_down(t, off);
        if (lane == 0) ssum += sqrtf(t);
    }
    if (lane == 0) qsum[q] = ssum;
}

__global__ void knn_reduce(const float* __restrict__ qsum, float* __restrict__ out, int Q) {
    const int lane = threadIdx.x;
    float v = 0.f;
    for (int i = lane; i < Q; i += 64) v += qsum[i];
#pragma unroll
    for (int off = 32; off > 0; off >>= 1) v += __shfl_down(v, off);
    if (lane == 0) out[0] = v / (float)(Q * KNN);
}

extern "C" void kernel_launch(void* const* d_in, const int* in_sizes, int n_in,
                              void* d_out, int out_size, void* d_ws, size_t ws_size,
                              hipStream_t stream) {
    (void)n_in; (void)out_size; (void)ws_size;
    const float* emb = (const float*)d_in[0];
    const float* mem = (const float*)d_in[1];
    const int Q  = in_sizes[0] / DDIM;       // 256
    const int N  = in_sizes[1] / DDIM;       // 200000
    const int NC = (N + MT - 1) / MT;        // 1563

    float*          cand = (float*)d_ws;                                         // NC*Q*5*4B ~ 8 MB
    float*          qsum = (float*)((char*)d_ws + (size_t)NC * Q * KNN * 4);     // 1 KB
    unsigned short* qbf  = (unsigned short*)((char*)d_ws + (size_t)NC * Q * KNN * 4 + 1024);

    conv_q<<<(Q * DDIM / 4 + 255) / 256, 256, 0, stream>>>(emb, qbf);
    knn_partial<<<NC, NT, 0, stream>>>(mem, qbf, cand, N);
    knn_merge_exact<<<Q, 64, 0, stream>>>(emb, mem, cand, qsum, Q, NC);
    knn_reduce<<<1, 64, 0, stream>>>(qsum, (float*)d_out, Q);
}